// Round 1
// baseline (1324.426 us; speedup 1.0000x reference)
//
#include <hip/hip_runtime.h>
#include <math.h>

#define T_DIM 2048
#define B_DIM 16
#define D_DIM 1024
#define N_DIM 64
#define EPSV 1e-6f

// proj layout: proj[m][c], m = t*B + b in [0, 32768), c: 0-63 k(->k_norm), 64-127 v, 128-191 q, 192-255 beta(sigmoided)
#define KC 32
#define MT 64
#define NT 256

__device__ __forceinline__ float tanh_fast(float x) {
    float e = __expf(2.f * x);
    return 1.f - 2.f / (e + 1.f);   // stable: e=inf -> 1, e=0 -> -1
}
__device__ __forceinline__ float sigmoid_fast(float x) {
    return 1.f / (1.f + __expf(-x));
}

__global__ __launch_bounds__(256) void proj_gemm(
    const float* __restrict__ x,
    const float* __restrict__ Wk, const float* __restrict__ Wv,
    const float* __restrict__ Wq, const float* __restrict__ Wb,
    const float* __restrict__ bb,
    float* __restrict__ proj)
{
    __shared__ float xs[KC][MT + 4];   // +4 pad keeps 16B align, shifts banks
    __shared__ float wsm[KC][NT + 4];
    const int tid = threadIdx.x;
    const int m0 = blockIdx.x * MT;
    const int tr = tid & 7;    // row group: rows 8*tr .. 8*tr+7
    const int tc = tid >> 3;   // col group [0,32): cols 4*tc..+3 and 128+4*tc..+3
    const float* Wmat[4] = {Wk, Wv, Wq, Wb};

    float acc[8][8];
    #pragma unroll
    for (int r = 0; r < 8; ++r)
        #pragma unroll
        for (int c = 0; c < 8; ++c) acc[r][c] = 0.f;

    for (int ch = 0; ch < D_DIM / KC; ++ch) {
        const int kb = ch * KC;
        // stage x tile: 64 rows x 32 k
        #pragma unroll
        for (int p = 0; p < 2; ++p) {
            int idx = tid + p * 256;
            int row = idx >> 3, kq = idx & 7;
            const float4 a = *(const float4*)(x + (size_t)(m0 + row) * D_DIM + kb + 4 * kq);
            xs[4*kq+0][row] = a.x; xs[4*kq+1][row] = a.y;
            xs[4*kq+2][row] = a.z; xs[4*kq+3][row] = a.w;
        }
        // stage W tile: 256 cols x 32 k
        #pragma unroll
        for (int p = 0; p < 8; ++p) {
            int idx = tid + p * 256;
            int c = idx >> 3, kq = idx & 7;
            const float* Wsrc = Wmat[c >> 6];
            const float4 a = *(const float4*)(Wsrc + (size_t)(c & 63) * D_DIM + kb + 4 * kq);
            wsm[4*kq+0][c] = a.x; wsm[4*kq+1][c] = a.y;
            wsm[4*kq+2][c] = a.z; wsm[4*kq+3][c] = a.w;
        }
        __syncthreads();
        #pragma unroll
        for (int kk = 0; kk < KC; ++kk) {
            float4 a0 = *(const float4*)&xs[kk][8 * tr];
            float4 a1 = *(const float4*)&xs[kk][8 * tr + 4];
            float4 b0 = *(const float4*)&wsm[kk][4 * tc];
            float4 b1 = *(const float4*)&wsm[kk][128 + 4 * tc];
            float av[8] = {a0.x, a0.y, a0.z, a0.w, a1.x, a1.y, a1.z, a1.w};
            float bv[8] = {b0.x, b0.y, b0.z, b0.w, b1.x, b1.y, b1.z, b1.w};
            #pragma unroll
            for (int r = 0; r < 8; ++r)
                #pragma unroll
                for (int c = 0; c < 8; ++c)
                    acc[r][c] += av[r] * bv[c];
        }
        __syncthreads();
    }

    // epilogue: group A cols = 4*tc+cc (raw), group B cols = 128+4*tc+cc (sigmoid+bias iff col>=192)
    const bool isbeta = (tc >= 16);
    float bias[4] = {0.f, 0.f, 0.f, 0.f};
    if (isbeta) {
        #pragma unroll
        for (int cc = 0; cc < 4; ++cc) bias[cc] = bb[4 * tc - 64 + cc];
    }
    #pragma unroll
    for (int r = 0; r < 8; ++r) {
        const size_t row = (size_t)(m0 + 8 * tr + r);
        float4 ga = make_float4(acc[r][0], acc[r][1], acc[r][2], acc[r][3]);
        float4 gb = make_float4(acc[r][4], acc[r][5], acc[r][6], acc[r][7]);
        if (isbeta) {
            gb.x = sigmoid_fast(gb.x + bias[0]);
            gb.y = sigmoid_fast(gb.y + bias[1]);
            gb.z = sigmoid_fast(gb.z + bias[2]);
            gb.w = sigmoid_fast(gb.w + bias[3]);
        }
        *(float4*)(proj + row * NT + 4 * tc)       = ga;
        *(float4*)(proj + row * NT + 128 + 4 * tc) = gb;
    }
}

// normalize k rows in place: kn = k / (||k|| + eps)
__global__ __launch_bounds__(256) void knorm_kernel(float* __restrict__ proj)
{
    const int w = (int)((blockIdx.x * blockDim.x + threadIdx.x) >> 6);  // row m
    const int lane = threadIdx.x & 63;
    float k = proj[(size_t)w * NT + lane];
    float s = k * k;
    #pragma unroll
    for (int off = 32; off; off >>= 1) s += __shfl_xor(s, off, 64);
    proj[(size_t)w * NT + lane] = k / (sqrtf(s) + EPSV);
}

// one wave per (b, i): lane j holds S[b][i][j]
__global__ __launch_bounds__(256) void recur_kernel(
    const float* __restrict__ proj,
    const float* __restrict__ S0,
    float* __restrict__ out)   // [T,B,N] then S_final [B,N,N]
{
    const int rid = (blockIdx.x << 2) + (threadIdx.x >> 6);  // [0, 1024)
    const int lane = threadIdx.x & 63;
    const int b = rid >> 6;
    const int i = rid & 63;

    float S = S0[(size_t)(b * 64 + i) * 64 + lane];
    const size_t stride = (size_t)B_DIM * NT;
    const float* p = proj + (size_t)b * NT;   // t = 0

    // step 0
    float kn = p[lane];
    float v  = p[64 + i];
    float q_prev = p[128 + lane];
    float be = p[192 + i];
    {
        float y = S * kn;
        #pragma unroll
        for (int off = 32; off; off >>= 1) y += __shfl_xor(y, off, 64);
        float delta = v - y;
        S = tanh_fast(be * S + delta * kn);
    }

    // prefetch t = 1
    p += stride;
    float kn_n = p[lane];
    float v_n  = p[64 + i];
    float q_n  = p[128 + lane];
    float be_n = p[192 + i];

    for (int t = 1; t < T_DIM; ++t) {
        float kn1 = kn_n, v1 = v_n, q1 = q_n, be1 = be_n;
        // issue prefetch for t+1 (clamped at the end; redundant load, no branch)
        const float* pn = proj + (size_t)((t + 1 < T_DIM) ? (t + 1) : t) * stride + (size_t)b * NT;
        kn_n = pn[lane];
        v_n  = pn[64 + i];
        q_n  = pn[128 + lane];
        be_n = pn[192 + i];

        // dual butterfly: Sq of step t-1 and retrieved of step t, both over current S
        float y1 = S * q_prev;
        float y2 = S * kn1;
        #pragma unroll
        for (int off = 32; off; off >>= 1) {
            y1 += __shfl_xor(y1, off, 64);
            y2 += __shfl_xor(y2, off, 64);
        }
        if (lane == 0) {
            out[(size_t)(t - 1) * (B_DIM * N_DIM) + b * 64 + i] = y1 * y1 * sigmoid_fast(y1);
        }
        float delta = v1 - y2;
        S = tanh_fast(be1 * S + delta * kn1);
        q_prev = q1;
    }

    // final Sq (step T-1)
    {
        float y1 = S * q_prev;
        #pragma unroll
        for (int off = 32; off; off >>= 1) y1 += __shfl_xor(y1, off, 64);
        if (lane == 0) {
            out[(size_t)(T_DIM - 1) * (B_DIM * N_DIM) + b * 64 + i] = y1 * y1 * sigmoid_fast(y1);
        }
    }
    // S_final
    out[(size_t)T_DIM * B_DIM * N_DIM + (size_t)(b * 64 + i) * 64 + lane] = S;
}

extern "C" void kernel_launch(void* const* d_in, const int* in_sizes, int n_in,
                              void* d_out, int out_size, void* d_ws, size_t ws_size,
                              hipStream_t stream) {
    const float* x  = (const float*)d_in[0];
    const float* S0 = (const float*)d_in[1];
    const float* Wk = (const float*)d_in[2];
    const float* Wv = (const float*)d_in[3];
    const float* Wq = (const float*)d_in[4];
    const float* Wb = (const float*)d_in[5];
    const float* bb = (const float*)d_in[6];
    float* out  = (float*)d_out;
    float* proj = (float*)d_ws;   // 32768 * 256 floats = 32 MB

    proj_gemm<<<dim3(32768 / MT), dim3(256), 0, stream>>>(x, Wk, Wv, Wq, Wb, bb, proj);
    knorm_kernel<<<dim3((32768 * 64) / 256), dim3(256), 0, stream>>>(proj);
    recur_kernel<<<dim3(256), dim3(256), 0, stream>>>(proj, S0, out);
}

// Round 2
// 1043.151 us; speedup vs baseline: 1.2696x; 1.2696x over previous
//
#include <hip/hip_runtime.h>
#include <math.h>

#define T_DIM 2048
#define B_DIM 16
#define D_DIM 1024
#define N_DIM 64
#define EPSV 1e-6f

// proj layout: proj[m][c], m = t*B + b in [0, 32768), c: 0-63 k(->k_norm), 64-127 v, 128-191 q, 192-255 beta(sigmoided)
#define KC 32
#define MT 64
#define NT 256

__device__ __forceinline__ float tanh_fast(float x) {
    float e = __expf(2.f * x);
    return 1.f - 2.f / (e + 1.f);   // stable: e=inf -> 1, e=0 -> -1
}
__device__ __forceinline__ float sigmoid_fast(float x) {
    return 1.f / (1.f + __expf(-x));
}

// DPP all-reduce within each 16-lane row: quad_perm xor1, xor2, row_ror:4, row_ror:8.
// All VALU-latency ops, no LDS pipe.
template<int CTRL>
__device__ __forceinline__ float dpp_radd(float x) {
    int y = __builtin_amdgcn_update_dpp(0, __float_as_int(x), CTRL, 0xf, 0xf, true);
    return x + __int_as_float(y);
}
__device__ __forceinline__ float reduce16(float x) {
    x = dpp_radd<0xB1>(x);    // quad_perm [1,0,3,2]  (xor 1)
    x = dpp_radd<0x4E>(x);    // quad_perm [2,3,0,1]  (xor 2)
    x = dpp_radd<0x124>(x);   // row_ror:4
    x = dpp_radd<0x128>(x);   // row_ror:8
    return x;
}

__global__ __launch_bounds__(256) void proj_gemm(
    const float* __restrict__ x,
    const float* __restrict__ Wk, const float* __restrict__ Wv,
    const float* __restrict__ Wq, const float* __restrict__ Wb,
    const float* __restrict__ bb,
    float* __restrict__ proj)
{
    __shared__ float xs[KC][MT + 4];
    __shared__ float wsm[KC][NT + 4];
    const int tid = threadIdx.x;
    const int m0 = blockIdx.x * MT;
    const int tr = tid & 7;
    const int tc = tid >> 3;
    const float* Wmat[4] = {Wk, Wv, Wq, Wb};

    float acc[8][8];
    #pragma unroll
    for (int r = 0; r < 8; ++r)
        #pragma unroll
        for (int c = 0; c < 8; ++c) acc[r][c] = 0.f;

    for (int ch = 0; ch < D_DIM / KC; ++ch) {
        const int kb = ch * KC;
        #pragma unroll
        for (int p = 0; p < 2; ++p) {
            int idx = tid + p * 256;
            int row = idx >> 3, kq = idx & 7;
            const float4 a = *(const float4*)(x + (size_t)(m0 + row) * D_DIM + kb + 4 * kq);
            xs[4*kq+0][row] = a.x; xs[4*kq+1][row] = a.y;
            xs[4*kq+2][row] = a.z; xs[4*kq+3][row] = a.w;
        }
        #pragma unroll
        for (int p = 0; p < 8; ++p) {
            int idx = tid + p * 256;
            int c = idx >> 3, kq = idx & 7;
            const float* Wsrc = Wmat[c >> 6];
            const float4 a = *(const float4*)(Wsrc + (size_t)(c & 63) * D_DIM + kb + 4 * kq);
            wsm[4*kq+0][c] = a.x; wsm[4*kq+1][c] = a.y;
            wsm[4*kq+2][c] = a.z; wsm[4*kq+3][c] = a.w;
        }
        __syncthreads();
        #pragma unroll
        for (int kk = 0; kk < KC; ++kk) {
            float4 a0 = *(const float4*)&xs[kk][8 * tr];
            float4 a1 = *(const float4*)&xs[kk][8 * tr + 4];
            float4 b0 = *(const float4*)&wsm[kk][4 * tc];
            float4 b1 = *(const float4*)&wsm[kk][128 + 4 * tc];
            float av[8] = {a0.x, a0.y, a0.z, a0.w, a1.x, a1.y, a1.z, a1.w};
            float bv[8] = {b0.x, b0.y, b0.z, b0.w, b1.x, b1.y, b1.z, b1.w};
            #pragma unroll
            for (int r = 0; r < 8; ++r)
                #pragma unroll
                for (int c = 0; c < 8; ++c)
                    acc[r][c] += av[r] * bv[c];
        }
        __syncthreads();
    }

    const bool isbeta = (tc >= 16);
    float bias[4] = {0.f, 0.f, 0.f, 0.f};
    if (isbeta) {
        #pragma unroll
        for (int cc = 0; cc < 4; ++cc) bias[cc] = bb[4 * tc - 64 + cc];
    }
    #pragma unroll
    for (int r = 0; r < 8; ++r) {
        const size_t row = (size_t)(m0 + 8 * tr + r);
        float4 ga = make_float4(acc[r][0], acc[r][1], acc[r][2], acc[r][3]);
        float4 gb = make_float4(acc[r][4], acc[r][5], acc[r][6], acc[r][7]);
        if (isbeta) {
            gb.x = sigmoid_fast(gb.x + bias[0]);
            gb.y = sigmoid_fast(gb.y + bias[1]);
            gb.z = sigmoid_fast(gb.z + bias[2]);
            gb.w = sigmoid_fast(gb.w + bias[3]);
        }
        *(float4*)(proj + row * NT + 4 * tc)       = ga;
        *(float4*)(proj + row * NT + 128 + 4 * tc) = gb;
    }
}

__global__ __launch_bounds__(256) void knorm_kernel(float* __restrict__ proj)
{
    const int w = (int)((blockIdx.x * blockDim.x + threadIdx.x) >> 6);
    const int lane = threadIdx.x & 63;
    float k = proj[(size_t)w * NT + lane];
    float s = k * k;
    #pragma unroll
    for (int off = 32; off; off >>= 1) s += __shfl_xor(s, off, 64);
    proj[(size_t)w * NT + lane] = k / (sqrtf(s) + EPSV);
}

// 4 rows per wave: lane = 16*r + l; row i = 4*(wid&15) + r; lane holds S[b][i][4l..4l+3].
// 16-lane DPP all-reduce (VALU latency) replaces the 6-stage 64-lane shfl chain.
// Register prefetch ring, depth 4, to hide L2/HBM latency against the short step.
__global__ __launch_bounds__(256) void recur2_kernel(
    const float* __restrict__ proj,
    const float* __restrict__ S0,
    float* __restrict__ out)   // [T,B,N] then S_final [B,N,N]
{
    const int wid  = (int)((blockIdx.x * 256 + threadIdx.x) >> 6);  // [0,256)
    const int lane = threadIdx.x & 63;
    const int l = lane & 15;
    const int r = lane >> 4;
    const int b = wid >> 4;
    const int i = ((wid & 15) << 2) + r;

    const float* pb = proj + (size_t)b * NT;
    const size_t stride = (size_t)B_DIM * NT;

    float4 s = *(const float4*)(S0 + ((size_t)(b * 64 + i) << 6) + 4 * l);

    float4 knb[4], qb[4];
    float  vb[4], beb[4];
    #pragma unroll
    for (int ph = 0; ph < 4; ++ph) {
        const float* pt = pb + (size_t)ph * stride;
        knb[ph] = *(const float4*)(pt + 4 * l);
        qb[ph]  = *(const float4*)(pt + 128 + 4 * l);
        vb[ph]  = pt[64 + i];
        beb[ph] = pt[192 + i];
    }

    for (int t0 = 0; t0 < T_DIM; t0 += 4) {
        #pragma unroll
        for (int ph = 0; ph < 4; ++ph) {
            const int t = t0 + ph;
            const float4 kn = knb[ph];
            const float4 q  = qb[ph];
            const float  v  = vb[ph];
            const float  be = beb[ph];

            int tp = t + 4; if (tp > T_DIM - 1) tp = T_DIM - 1;
            const float* pt = pb + (size_t)tp * stride;
            knb[ph] = *(const float4*)(pt + 4 * l);
            qb[ph]  = *(const float4*)(pt + 128 + 4 * l);
            vb[ph]  = pt[64 + i];
            beb[ph] = pt[192 + i];

            // retrieved = S . kn  (16-lane DPP all-reduce)
            float y2 = (s.x * kn.x + s.y * kn.y) + (s.z * kn.z + s.w * kn.w);
            y2 = reduce16(y2);
            const float delta = v - y2;

            s.x = tanh_fast(fmaf(be, s.x, delta * kn.x));
            s.y = tanh_fast(fmaf(be, s.y, delta * kn.y));
            s.z = tanh_fast(fmaf(be, s.z, delta * kn.z));
            s.w = tanh_fast(fmaf(be, s.w, delta * kn.w));

            // Sq = S_new . q ; off the S-critical-path, overlaps next step
            float y1 = (s.x * q.x + s.y * q.y) + (s.z * q.z + s.w * q.w);
            y1 = reduce16(y1);
            if (l == 0) {
                out[(size_t)t * (B_DIM * N_DIM) + b * 64 + i] = y1 * y1 * sigmoid_fast(y1);
            }
        }
    }

    *(float4*)(out + (size_t)T_DIM * B_DIM * N_DIM + ((size_t)(b * 64 + i) << 6) + 4 * l) = s;
}

extern "C" void kernel_launch(void* const* d_in, const int* in_sizes, int n_in,
                              void* d_out, int out_size, void* d_ws, size_t ws_size,
                              hipStream_t stream) {
    const float* x  = (const float*)d_in[0];
    const float* S0 = (const float*)d_in[1];
    const float* Wk = (const float*)d_in[2];
    const float* Wv = (const float*)d_in[3];
    const float* Wq = (const float*)d_in[4];
    const float* Wb = (const float*)d_in[5];
    const float* bb = (const float*)d_in[6];
    float* out  = (float*)d_out;
    float* proj = (float*)d_ws;   // 32768 * 256 floats = 32 MB

    proj_gemm<<<dim3(32768 / MT), dim3(256), 0, stream>>>(x, Wk, Wv, Wq, Wb, bb, proj);
    knorm_kernel<<<dim3((32768 * 64) / 256), dim3(256), 0, stream>>>(proj);
    recur2_kernel<<<dim3(64), dim3(256), 0, stream>>>(proj, S0, out);
}

// Round 4
// 988.322 us; speedup vs baseline: 1.3401x; 1.0555x over previous
//
#include <hip/hip_runtime.h>
#include <math.h>

#define T_DIM 2048
#define B_DIM 16
#define D_DIM 1024
#define N_DIM 64
#define EPSV 1e-6f

// proj layout: proj[m][c], m = t*B + b in [0, 32768), c: 0-63 k(->k_norm), 64-127 v, 128-191 q, 192-255 beta(sigmoided)
#define KC 32
#define MT 64
#define NT 256

#define TWO_LOG2E 2.885390081777927f   // 2*log2(e)

__device__ __forceinline__ float sigmoid_fast(float x) {
    return 1.f / (1.f + __expf(-x));
}
// tanh(x) = 1 - 2/(exp2(2*log2e*x)+1); caller pre-scales by TWO_LOG2E
__device__ __forceinline__ float tanh_from_scaled(float xs) {
    float e = __builtin_amdgcn_exp2f(xs);    // v_exp_f32: 2^xs
    return 1.f - 2.f / (e + 1.f);
}

// DPP all-reduce within each 16-lane row: quad_perm xor1, xor2, row_ror:4, row_ror:8.
template<int CTRL>
__device__ __forceinline__ float dpp_radd(float x) {
    int y = __builtin_amdgcn_update_dpp(0, __float_as_int(x), CTRL, 0xf, 0xf, true);
    return x + __int_as_float(y);
}
__device__ __forceinline__ float reduce16(float x) {
    x = dpp_radd<0xB1>(x);    // quad_perm [1,0,3,2]
    x = dpp_radd<0x4E>(x);    // quad_perm [2,3,0,1]
    x = dpp_radd<0x124>(x);   // row_ror:4
    x = dpp_radd<0x128>(x);   // row_ror:8
    return x;
}

__global__ __launch_bounds__(256) void proj_gemm(
    const float* __restrict__ x,
    const float* __restrict__ Wk, const float* __restrict__ Wv,
    const float* __restrict__ Wq, const float* __restrict__ Wb,
    const float* __restrict__ bb,
    float* __restrict__ proj)
{
    __shared__ float xs[KC][MT + 4];
    __shared__ float wsm[KC][NT + 4];
    const int tid = threadIdx.x;
    const int m0 = blockIdx.x * MT;
    const int tr = tid & 7;
    const int tc = tid >> 3;
    const float* Wmat[4] = {Wk, Wv, Wq, Wb};

    float acc[8][8];
    #pragma unroll
    for (int r = 0; r < 8; ++r)
        #pragma unroll
        for (int c = 0; c < 8; ++c) acc[r][c] = 0.f;

    for (int ch = 0; ch < D_DIM / KC; ++ch) {
        const int kb = ch * KC;
        #pragma unroll
        for (int p = 0; p < 2; ++p) {
            int idx = tid + p * 256;
            int row = idx >> 3, kq = idx & 7;
            const float4 a = *(const float4*)(x + (size_t)(m0 + row) * D_DIM + kb + 4 * kq);
            xs[4*kq+0][row] = a.x; xs[4*kq+1][row] = a.y;
            xs[4*kq+2][row] = a.z; xs[4*kq+3][row] = a.w;
        }
        #pragma unroll
        for (int p = 0; p < 8; ++p) {
            int idx = tid + p * 256;
            int c = idx >> 3, kq = idx & 7;
            const float* Wsrc = Wmat[c >> 6];
            const float4 a = *(const float4*)(Wsrc + (size_t)(c & 63) * D_DIM + kb + 4 * kq);
            wsm[4*kq+0][c] = a.x; wsm[4*kq+1][c] = a.y;
            wsm[4*kq+2][c] = a.z; wsm[4*kq+3][c] = a.w;
        }
        __syncthreads();
        #pragma unroll
        for (int kk = 0; kk < KC; ++kk) {
            float4 a0 = *(const float4*)&xs[kk][8 * tr];
            float4 a1 = *(const float4*)&xs[kk][8 * tr + 4];
            float4 b0 = *(const float4*)&wsm[kk][4 * tc];
            float4 b1 = *(const float4*)&wsm[kk][128 + 4 * tc];
            float av[8] = {a0.x, a0.y, a0.z, a0.w, a1.x, a1.y, a1.z, a1.w};
            float bv[8] = {b0.x, b0.y, b0.z, b0.w, b1.x, b1.y, b1.z, b1.w};
            #pragma unroll
            for (int r = 0; r < 8; ++r)
                #pragma unroll
                for (int c = 0; c < 8; ++c)
                    acc[r][c] += av[r] * bv[c];
        }
        __syncthreads();
    }

    const bool isbeta = (tc >= 16);
    float bias[4] = {0.f, 0.f, 0.f, 0.f};
    if (isbeta) {
        #pragma unroll
        for (int cc = 0; cc < 4; ++cc) bias[cc] = bb[4 * tc - 64 + cc];
    }
    #pragma unroll
    for (int r = 0; r < 8; ++r) {
        const size_t row = (size_t)(m0 + 8 * tr + r);
        float4 ga = make_float4(acc[r][0], acc[r][1], acc[r][2], acc[r][3]);
        float4 gb = make_float4(acc[r][4], acc[r][5], acc[r][6], acc[r][7]);
        if (isbeta) {
            gb.x = sigmoid_fast(gb.x + bias[0]);
            gb.y = sigmoid_fast(gb.y + bias[1]);
            gb.z = sigmoid_fast(gb.z + bias[2]);
            gb.w = sigmoid_fast(gb.w + bias[3]);
        }
        *(float4*)(proj + row * NT + 4 * tc)       = ga;
        *(float4*)(proj + row * NT + 128 + 4 * tc) = gb;
    }
}

__global__ __launch_bounds__(256) void knorm_kernel(float* __restrict__ proj)
{
    const int w = (int)((blockIdx.x * blockDim.x + threadIdx.x) >> 6);
    const int lane = threadIdx.x & 63;
    float k = proj[(size_t)w * NT + lane];
    float s = k * k;
    #pragma unroll
    for (int off = 32; off; off >>= 1) s += __shfl_xor(s, off, 64);
    proj[(size_t)w * NT + lane] = k / (sqrtf(s) + EPSV);
}

// 4 rows per wave, 16 lanes per row, float4 of S per lane.
// DEPTH-8 register prefetch ring. __launch_bounds__(256,1) lifts the VGPR
// budget to ~512 so the scheduler cannot sink the ring loads (round-2 failure:
// VGPR=44 proved the ring collapsed to depth~1 -> full HBM latency per step).
#define DEPTH 8
__global__ __launch_bounds__(256, 1) void recur3_kernel(
    const float* __restrict__ proj,
    const float* __restrict__ S0,
    float* __restrict__ out)   // [T,B,N] then S_final [B,N,N]
{
    const int wid  = (int)((blockIdx.x * 256 + threadIdx.x) >> 6);  // [0,256)
    const int lane = threadIdx.x & 63;
    const int l = lane & 15;
    const int r = lane >> 4;
    const int b = wid >> 4;
    const int i = ((wid & 15) << 2) + r;

    const float* pb = proj + (size_t)b * NT;
    const size_t stride = (size_t)B_DIM * NT;

    float4 s = *(const float4*)(S0 + ((size_t)(b * 64 + i) << 6) + 4 * l);

    float4 knb[DEPTH], qb[DEPTH];
    float  vb[DEPTH], beb[DEPTH];
    #pragma unroll
    for (int ph = 0; ph < DEPTH; ++ph) {
        const float* pt = pb + (size_t)ph * stride;
        knb[ph] = *(const float4*)(pt + 4 * l);
        qb[ph]  = *(const float4*)(pt + 128 + 4 * l);
        vb[ph]  = pt[64 + i];
        beb[ph] = pt[192 + i];
    }

    for (int t0 = 0; t0 < T_DIM; t0 += DEPTH) {
        #pragma unroll
        for (int ph = 0; ph < DEPTH; ++ph) {
            const int t = t0 + ph;
            const float4 kn = knb[ph];
            const float4 q  = qb[ph];
            const float  v  = vb[ph];
            const float  be = beb[ph];

            int tp = t + DEPTH; if (tp > T_DIM - 1) tp = T_DIM - 1;
            const float* pt = pb + (size_t)tp * stride;
            knb[ph] = *(const float4*)(pt + 4 * l);
            qb[ph]  = *(const float4*)(pt + 128 + 4 * l);
            vb[ph]  = pt[64 + i];
            beb[ph] = pt[192 + i];

            // retrieved = S . kn  (16-lane DPP all-reduce) — the critical path
            float y2 = (s.x * kn.x + s.y * kn.y) + (s.z * kn.z + s.w * kn.w);
            y2 = reduce16(y2);
            const float delta = (v - y2) * TWO_LOG2E;         // fold 2*log2e here
            const float bes = be * TWO_LOG2E;                 // off critical path

            s.x = tanh_from_scaled(fmaf(bes, s.x, delta * kn.x));
            s.y = tanh_from_scaled(fmaf(bes, s.y, delta * kn.y));
            s.z = tanh_from_scaled(fmaf(bes, s.z, delta * kn.z));
            s.w = tanh_from_scaled(fmaf(bes, s.w, delta * kn.w));

            // Sq = S_new . q ; off the S-critical-path, overlaps next step
            float y1 = (s.x * q.x + s.y * q.y) + (s.z * q.z + s.w * q.w);
            y1 = reduce16(y1);
            if (l == 0) {
                out[(size_t)t * (B_DIM * N_DIM) + b * 64 + i] = y1 * y1 * sigmoid_fast(y1);
            }
        }
    }

    *(float4*)(out + (size_t)T_DIM * B_DIM * N_DIM + ((size_t)(b * 64 + i) << 6) + 4 * l) = s;
}

extern "C" void kernel_launch(void* const* d_in, const int* in_sizes, int n_in,
                              void* d_out, int out_size, void* d_ws, size_t ws_size,
                              hipStream_t stream) {
    const float* x  = (const float*)d_in[0];
    const float* S0 = (const float*)d_in[1];
    const float* Wk = (const float*)d_in[2];
    const float* Wv = (const float*)d_in[3];
    const float* Wq = (const float*)d_in[4];
    const float* Wb = (const float*)d_in[5];
    const float* bb = (const float*)d_in[6];
    float* out  = (float*)d_out;
    float* proj = (float*)d_ws;   // 32768 * 256 floats = 32 MB

    proj_gemm<<<dim3(32768 / MT), dim3(256), 0, stream>>>(x, Wk, Wv, Wq, Wb, bb, proj);
    knorm_kernel<<<dim3((32768 * 64) / 256), dim3(256), 0, stream>>>(proj);
    recur3_kernel<<<dim3(64), dim3(256), 0, stream>>>(proj, S0, out);
}

// Round 5
// 947.646 us; speedup vs baseline: 1.3976x; 1.0429x over previous
//
#include <hip/hip_runtime.h>
#include <math.h>

#define T_DIM 2048
#define B_DIM 16
#define D_DIM 1024
#define N_DIM 64
#define EPSV 1e-6f

// proj layout: proj[m][c], m = t*B + b in [0, 32768), c: 0-63 k(->k_norm), 64-127 v, 128-191 q, 192-255 beta(sigmoided)
#define KC 32
#define MT 64
#define NT 256

#define TWO_LOG2E 2.885390081777927f   // 2*log2(e)

__device__ __forceinline__ float sigmoid_fast(float x) {
    return 1.f / (1.f + __expf(-x));
}
// tanh(x) = 1 - 2/(exp2(2*log2e*x)+1); caller pre-scales by TWO_LOG2E
__device__ __forceinline__ float tanh_from_scaled(float xs) {
    float e = __builtin_amdgcn_exp2f(xs);    // v_exp_f32: 2^xs
    return 1.f - 2.f / (e + 1.f);
}

// DPP all-reduce within each 16-lane row: quad_perm xor1, xor2, row_ror:4, row_ror:8.
template<int CTRL>
__device__ __forceinline__ float dpp_radd(float x) {
    int y = __builtin_amdgcn_update_dpp(0, __float_as_int(x), CTRL, 0xf, 0xf, true);
    return x + __int_as_float(y);
}
__device__ __forceinline__ float reduce16(float x) {
    x = dpp_radd<0xB1>(x);    // quad_perm [1,0,3,2]
    x = dpp_radd<0x4E>(x);    // quad_perm [2,3,0,1]
    x = dpp_radd<0x124>(x);   // row_ror:4
    x = dpp_radd<0x128>(x);   // row_ror:8
    return x;
}

// async global -> LDS DMA, 16 B per lane; lptr is wave-uniform base, lane i lands at base + 16*i
__device__ __forceinline__ void dma16(const float* g, float* l) {
    __builtin_amdgcn_global_load_lds((const __attribute__((address_space(1))) void*)g,
                                     (__attribute__((address_space(3))) void*)l, 16, 0, 0);
}

__global__ __launch_bounds__(256) void proj_gemm(
    const float* __restrict__ x,
    const float* __restrict__ Wk, const float* __restrict__ Wv,
    const float* __restrict__ Wq, const float* __restrict__ Wb,
    const float* __restrict__ bb,
    float* __restrict__ proj)
{
    __shared__ float xs[KC][MT + 4];
    __shared__ float wsm[KC][NT + 4];
    const int tid = threadIdx.x;
    const int m0 = blockIdx.x * MT;
    const int tr = tid & 7;
    const int tc = tid >> 3;
    const float* Wmat[4] = {Wk, Wv, Wq, Wb};

    float acc[8][8];
    #pragma unroll
    for (int r = 0; r < 8; ++r)
        #pragma unroll
        for (int c = 0; c < 8; ++c) acc[r][c] = 0.f;

    for (int ch = 0; ch < D_DIM / KC; ++ch) {
        const int kb = ch * KC;
        #pragma unroll
        for (int p = 0; p < 2; ++p) {
            int idx = tid + p * 256;
            int row = idx >> 3, kq = idx & 7;
            const float4 a = *(const float4*)(x + (size_t)(m0 + row) * D_DIM + kb + 4 * kq);
            xs[4*kq+0][row] = a.x; xs[4*kq+1][row] = a.y;
            xs[4*kq+2][row] = a.z; xs[4*kq+3][row] = a.w;
        }
        #pragma unroll
        for (int p = 0; p < 8; ++p) {
            int idx = tid + p * 256;
            int c = idx >> 3, kq = idx & 7;
            const float* Wsrc = Wmat[c >> 6];
            const float4 a = *(const float4*)(Wsrc + (size_t)(c & 63) * D_DIM + kb + 4 * kq);
            wsm[4*kq+0][c] = a.x; wsm[4*kq+1][c] = a.y;
            wsm[4*kq+2][c] = a.z; wsm[4*kq+3][c] = a.w;
        }
        __syncthreads();
        #pragma unroll
        for (int kk = 0; kk < KC; ++kk) {
            float4 a0 = *(const float4*)&xs[kk][8 * tr];
            float4 a1 = *(const float4*)&xs[kk][8 * tr + 4];
            float4 b0 = *(const float4*)&wsm[kk][4 * tc];
            float4 b1 = *(const float4*)&wsm[kk][128 + 4 * tc];
            float av[8] = {a0.x, a0.y, a0.z, a0.w, a1.x, a1.y, a1.z, a1.w};
            float bv[8] = {b0.x, b0.y, b0.z, b0.w, b1.x, b1.y, b1.z, b1.w};
            #pragma unroll
            for (int r = 0; r < 8; ++r)
                #pragma unroll
                for (int c = 0; c < 8; ++c)
                    acc[r][c] += av[r] * bv[c];
        }
        __syncthreads();
    }

    const bool isbeta = (tc >= 16);
    float bias[4] = {0.f, 0.f, 0.f, 0.f};
    if (isbeta) {
        #pragma unroll
        for (int cc = 0; cc < 4; ++cc) bias[cc] = bb[4 * tc - 64 + cc];
    }
    #pragma unroll
    for (int r = 0; r < 8; ++r) {
        const size_t row = (size_t)(m0 + 8 * tr + r);
        float4 ga = make_float4(acc[r][0], acc[r][1], acc[r][2], acc[r][3]);
        float4 gb = make_float4(acc[r][4], acc[r][5], acc[r][6], acc[r][7]);
        if (isbeta) {
            gb.x = sigmoid_fast(gb.x + bias[0]);
            gb.y = sigmoid_fast(gb.y + bias[1]);
            gb.z = sigmoid_fast(gb.z + bias[2]);
            gb.w = sigmoid_fast(gb.w + bias[3]);
        }
        *(float4*)(proj + row * NT + 4 * tc)       = ga;
        *(float4*)(proj + row * NT + 128 + 4 * tc) = gb;
    }
}

__global__ __launch_bounds__(256) void knorm_kernel(float* __restrict__ proj)
{
    const int w = (int)((blockIdx.x * blockDim.x + threadIdx.x) >> 6);
    const int lane = threadIdx.x & 63;
    float k = proj[(size_t)w * NT + lane];
    float s = k * k;
    #pragma unroll
    for (int off = 32; off; off >>= 1) s += __shfl_xor(s, off, 64);
    proj[(size_t)w * NT + lane] = k / (sqrtf(s) + EPSV);
}

// One wave per block (64 threads), one block per (b, group-of-4-rows).
// Superstep staging: while computing 16 steps from one LDS buffer, 16 async
// global_load_lds DMAs (1 KB row each, zero VGPR cost) fill the other buffer.
// The only DMA wait lands before the first read of the fresh buffer, 14 steps
// (~2000 cyc) after issue -> latency fully hidden. Distinct __shared__ arrays
// let AA prove per-step ds_reads don't alias in-flight DMAs.
__global__ __launch_bounds__(64, 1) void recur4_kernel(
    const float* __restrict__ proj,
    const float* __restrict__ S0,
    float* __restrict__ out)   // [T,B,N] then S_final [B,N,N]
{
    __shared__ float bufA[16][256];
    __shared__ float bufB[16][256];

    const int wid  = blockIdx.x;          // [0,256)
    const int lane = threadIdx.x;         // [0,64)
    const int l = lane & 15;
    const int r = lane >> 4;
    const int b = wid >> 4;
    const int i = ((wid & 15) << 2) + r;

    float4 s = *(const float4*)(S0 + ((size_t)(b * 64 + i) << 6) + 4 * l);

    // prologue: DMA rows 0..15 -> bufA
    #pragma unroll
    for (int j = 0; j < 16; ++j) {
        dma16(proj + ((size_t)j * B_DIM + b) * NT + 4 * lane, &bufA[j][0]);
    }

    float4 knr[4], qr[4];
    float  vr[4], ber[4];
    // initial register ring: rows 0,1 (compiler inserts the DMA wait here)
    #pragma unroll
    for (int j = 0; j < 2; ++j) {
        const float* src = &bufA[j][0];
        knr[j] = *(const float4*)(src + 4 * l);
        qr[j]  = *(const float4*)(src + 128 + 4 * l);
        vr[j]  = src[64 + i];
        ber[j] = src[192 + i];
    }

#define STEP(sph, CUR, NXT, t0)                                                 \
    {                                                                           \
        const int t = (t0) + (sph);                                             \
        const float4 kn = knr[(sph) & 3];                                       \
        const float4 q  = qr[(sph) & 3];                                        \
        const float  v  = vr[(sph) & 3];                                        \
        const float  be = ber[(sph) & 3];                                       \
        const float* src = ((sph) + 2 < 16) ? &CUR[(sph) + 2][0]                \
                                            : &NXT[(sph) + 2 - 16][0];          \
        knr[((sph) + 2) & 3] = *(const float4*)(src + 4 * l);                   \
        qr[((sph) + 2) & 3]  = *(const float4*)(src + 128 + 4 * l);             \
        vr[((sph) + 2) & 3]  = src[64 + i];                                     \
        ber[((sph) + 2) & 3] = src[192 + i];                                    \
        float y2 = (s.x * kn.x + s.y * kn.y) + (s.z * kn.z + s.w * kn.w);       \
        y2 = reduce16(y2);                                                      \
        const float delta = (v - y2) * TWO_LOG2E;                               \
        const float bes = be * TWO_LOG2E;                                       \
        s.x = tanh_from_scaled(fmaf(bes, s.x, delta * kn.x));                   \
        s.y = tanh_from_scaled(fmaf(bes, s.y, delta * kn.y));                   \
        s.z = tanh_from_scaled(fmaf(bes, s.z, delta * kn.z));                   \
        s.w = tanh_from_scaled(fmaf(bes, s.w, delta * kn.w));                   \
        float y1 = (s.x * q.x + s.y * q.y) + (s.z * q.z + s.w * q.w);           \
        y1 = reduce16(y1);                                                      \
        if (l == 0) {                                                           \
            out[(size_t)t * (B_DIM * N_DIM) + b * 64 + i] =                     \
                y1 * y1 * sigmoid_fast(y1);                                     \
        }                                                                       \
    }

    for (int t0 = 0; t0 < T_DIM; t0 += 32) {
        // phase A: compute rows t0..t0+15 from bufA; DMA rows t0+16..t0+31 -> bufB
        #pragma unroll
        for (int j = 0; j < 16; ++j) {
            int row = t0 + 16 + j; if (row > T_DIM - 1) row = T_DIM - 1;
            dma16(proj + ((size_t)row * B_DIM + b) * NT + 4 * lane, &bufB[j][0]);
        }
        #pragma unroll
        for (int sp = 0; sp < 16; ++sp) { STEP(sp, bufA, bufB, t0); }

        // phase B: compute rows t0+16..t0+31 from bufB; DMA rows t0+32.. -> bufA
        #pragma unroll
        for (int j = 0; j < 16; ++j) {
            int row = t0 + 32 + j; if (row > T_DIM - 1) row = T_DIM - 1;
            dma16(proj + ((size_t)row * B_DIM + b) * NT + 4 * lane, &bufA[j][0]);
        }
        #pragma unroll
        for (int sp = 0; sp < 16; ++sp) { STEP(sp, bufB, bufA, t0 + 16); }
    }
#undef STEP

    *(float4*)(out + (size_t)T_DIM * B_DIM * N_DIM + ((size_t)(b * 64 + i) << 6) + 4 * l) = s;
}

extern "C" void kernel_launch(void* const* d_in, const int* in_sizes, int n_in,
                              void* d_out, int out_size, void* d_ws, size_t ws_size,
                              hipStream_t stream) {
    const float* x  = (const float*)d_in[0];
    const float* S0 = (const float*)d_in[1];
    const float* Wk = (const float*)d_in[2];
    const float* Wv = (const float*)d_in[3];
    const float* Wq = (const float*)d_in[4];
    const float* Wb = (const float*)d_in[5];
    const float* bb = (const float*)d_in[6];
    float* out  = (float*)d_out;
    float* proj = (float*)d_ws;   // 32768 * 256 floats = 32 MB

    proj_gemm<<<dim3(32768 / MT), dim3(256), 0, stream>>>(x, Wk, Wv, Wq, Wb, bb, proj);
    knorm_kernel<<<dim3((32768 * 64) / 256), dim3(256), 0, stream>>>(proj);
    recur4_kernel<<<dim3(256), dim3(64), 0, stream>>>(proj, S0, out);
}

// Round 6
// 930.436 us; speedup vs baseline: 1.4234x; 1.0185x over previous
//
#include <hip/hip_runtime.h>
#include <math.h>

#define T_DIM 2048
#define B_DIM 16
#define D_DIM 1024
#define N_DIM 64
#define EPSV 1e-6f

// proj layout: proj[m][c], m = t*B + b in [0, 32768), c: 0-63 k(->k_norm), 64-127 v, 128-191 q, 192-255 beta(sigmoided)
#define KC 32
#define MT 64
#define NT 256

#define TWO_LOG2E 2.885390081777927f   // 2*log2(e)

__device__ __forceinline__ float sigmoid_fast(float x) {
    return 1.f / (1.f + __expf(-x));
}
// tanh(x) = 1 - 2/(exp2(2*log2e*x)+1); caller pre-scales by TWO_LOG2E
__device__ __forceinline__ float tanh_from_scaled(float xs) {
    float e = __builtin_amdgcn_exp2f(xs);    // v_exp_f32: 2^xs
    return 1.f - 2.f / (e + 1.f);
}

// DPP all-reduce within each 16-lane row: quad_perm xor1, xor2, row_ror:4, row_ror:8.
template<int CTRL>
__device__ __forceinline__ float dpp_radd(float x) {
    int y = __builtin_amdgcn_update_dpp(0, __float_as_int(x), CTRL, 0xf, 0xf, true);
    return x + __int_as_float(y);
}
__device__ __forceinline__ float reduce16(float x) {
    x = dpp_radd<0xB1>(x);    // quad_perm [1,0,3,2]
    x = dpp_radd<0x4E>(x);    // quad_perm [2,3,0,1]
    x = dpp_radd<0x124>(x);   // row_ror:4
    x = dpp_radd<0x128>(x);   // row_ror:8
    return x;
}

// async global -> LDS DMA, 16 B per lane; LDS base wave-uniform, lane i -> base + 16*i
__device__ __forceinline__ void dma16(const float* g, float* l) {
    __builtin_amdgcn_global_load_lds((const __attribute__((address_space(1))) void*)g,
                                     (__attribute__((address_space(3))) void*)l, 16, 0, 0);
}

__global__ __launch_bounds__(256) void proj_gemm(
    const float* __restrict__ x,
    const float* __restrict__ Wk, const float* __restrict__ Wv,
    const float* __restrict__ Wq, const float* __restrict__ Wb,
    const float* __restrict__ bb,
    float* __restrict__ proj)
{
    __shared__ float xs[KC][MT + 4];
    __shared__ float wsm[KC][NT + 4];
    const int tid = threadIdx.x;
    const int m0 = blockIdx.x * MT;
    const int tr = tid & 7;
    const int tc = tid >> 3;
    const float* Wmat[4] = {Wk, Wv, Wq, Wb};

    float acc[8][8];
    #pragma unroll
    for (int r = 0; r < 8; ++r)
        #pragma unroll
        for (int c = 0; c < 8; ++c) acc[r][c] = 0.f;

    for (int ch = 0; ch < D_DIM / KC; ++ch) {
        const int kb = ch * KC;
        #pragma unroll
        for (int p = 0; p < 2; ++p) {
            int idx = tid + p * 256;
            int row = idx >> 3, kq = idx & 7;
            const float4 a = *(const float4*)(x + (size_t)(m0 + row) * D_DIM + kb + 4 * kq);
            xs[4*kq+0][row] = a.x; xs[4*kq+1][row] = a.y;
            xs[4*kq+2][row] = a.z; xs[4*kq+3][row] = a.w;
        }
        #pragma unroll
        for (int p = 0; p < 8; ++p) {
            int idx = tid + p * 256;
            int c = idx >> 3, kq = idx & 7;
            const float* Wsrc = Wmat[c >> 6];
            const float4 a = *(const float4*)(Wsrc + (size_t)(c & 63) * D_DIM + kb + 4 * kq);
            wsm[4*kq+0][c] = a.x; wsm[4*kq+1][c] = a.y;
            wsm[4*kq+2][c] = a.z; wsm[4*kq+3][c] = a.w;
        }
        __syncthreads();
        #pragma unroll
        for (int kk = 0; kk < KC; ++kk) {
            float4 a0 = *(const float4*)&xs[kk][8 * tr];
            float4 a1 = *(const float4*)&xs[kk][8 * tr + 4];
            float4 b0 = *(const float4*)&wsm[kk][4 * tc];
            float4 b1 = *(const float4*)&wsm[kk][128 + 4 * tc];
            float av[8] = {a0.x, a0.y, a0.z, a0.w, a1.x, a1.y, a1.z, a1.w};
            float bv[8] = {b0.x, b0.y, b0.z, b0.w, b1.x, b1.y, b1.z, b1.w};
            #pragma unroll
            for (int r = 0; r < 8; ++r)
                #pragma unroll
                for (int c = 0; c < 8; ++c)
                    acc[r][c] += av[r] * bv[c];
        }
        __syncthreads();
    }

    const bool isbeta = (tc >= 16);
    float bias[4] = {0.f, 0.f, 0.f, 0.f};
    if (isbeta) {
        #pragma unroll
        for (int cc = 0; cc < 4; ++cc) bias[cc] = bb[4 * tc - 64 + cc];
    }
    #pragma unroll
    for (int r = 0; r < 8; ++r) {
        const size_t row = (size_t)(m0 + 8 * tr + r);
        float4 ga = make_float4(acc[r][0], acc[r][1], acc[r][2], acc[r][3]);
        float4 gb = make_float4(acc[r][4], acc[r][5], acc[r][6], acc[r][7]);
        if (isbeta) {
            gb.x = sigmoid_fast(gb.x + bias[0]);
            gb.y = sigmoid_fast(gb.y + bias[1]);
            gb.z = sigmoid_fast(gb.z + bias[2]);
            gb.w = sigmoid_fast(gb.w + bias[3]);
        }
        *(float4*)(proj + row * NT + 4 * tc)       = ga;
        *(float4*)(proj + row * NT + 128 + 4 * tc) = gb;
    }
}

__global__ __launch_bounds__(256) void knorm_kernel(float* __restrict__ proj)
{
    const int w = (int)((blockIdx.x * blockDim.x + threadIdx.x) >> 6);
    const int lane = threadIdx.x & 63;
    float k = proj[(size_t)w * NT + lane];
    float s = k * k;
    #pragma unroll
    for (int off = 32; off; off >>= 1) s += __shfl_xor(s, off, 64);
    proj[(size_t)w * NT + lane] = k / (sqrtf(s) + EPSV);
}

// One 16-step compute phase out of an already-filled LDS buffer.
__device__ __forceinline__ void phase16(const float (*buf)[256], int t0,
                                        float4& s, int l, int i, int b,
                                        float* __restrict__ out)
{
    float4 kr[2], qr[2];
    float  vr[2], ber[2];
    #pragma unroll
    for (int j = 0; j < 2; ++j) {
        const float* src = &buf[j][0];
        kr[j]  = *(const float4*)(src + 4 * l);
        qr[j]  = *(const float4*)(src + 128 + 4 * l);
        vr[j]  = src[64 + i];
        ber[j] = src[192 + i];
    }
    #pragma unroll
    for (int sp = 0; sp < 16; ++sp) {
        const float4 kn = kr[sp & 1];
        const float4 q  = qr[sp & 1];
        const float  v  = vr[sp & 1];
        const float  be = ber[sp & 1];
        if (sp + 2 < 16) {   // static (unrolled): ring never crosses the barrier
            const float* src = &buf[sp + 2][0];
            kr[sp & 1]  = *(const float4*)(src + 4 * l);
            qr[sp & 1]  = *(const float4*)(src + 128 + 4 * l);
            vr[sp & 1]  = src[64 + i];
            ber[sp & 1] = src[192 + i];
        }
        float y2 = (s.x * kn.x + s.y * kn.y) + (s.z * kn.z + s.w * kn.w);
        y2 = reduce16(y2);
        const float delta = (v - y2) * TWO_LOG2E;
        const float bes = be * TWO_LOG2E;
        s.x = tanh_from_scaled(fmaf(bes, s.x, delta * kn.x));
        s.y = tanh_from_scaled(fmaf(bes, s.y, delta * kn.y));
        s.z = tanh_from_scaled(fmaf(bes, s.z, delta * kn.z));
        s.w = tanh_from_scaled(fmaf(bes, s.w, delta * kn.w));
        float y1 = (s.x * q.x + s.y * q.y) + (s.z * q.z + s.w * q.w);
        y1 = reduce16(y1);
        if (l == 0) {
            out[(size_t)(t0 + sp) * (B_DIM * N_DIM) + b * 64 + i] =
                y1 * y1 * sigmoid_fast(y1);
        }
    }
}

// Warp-specialized producer/consumer. Wave 1 (producer) only issues
// global_load_lds DMAs and syncs: its barrier-side vmcnt(0) drain waits on ITS
// OWN DMAs, fully overlapped with the consumer's 16 compute steps. Wave 0
// (consumer) has no vmcnt ops except output stores (never waited mid-phase);
// its LDS ring needs only fine lgkmcnt waits. Waitcnt counters are per-wave,
// so the DMA latency can no longer poison the compute wave's scheduling
// (rounds 2-5 failure mode).
__global__ __launch_bounds__(128, 1) void recur5_kernel(
    const float* __restrict__ proj,
    const float* __restrict__ S0,
    float* __restrict__ out)   // [T,B,N] then S_final [B,N,N]
{
    __shared__ float bufA[16][256];
    __shared__ float bufB[16][256];

    const int wid  = blockIdx.x;          // [0,256)
    const int wv   = threadIdx.x >> 6;    // 0 = consumer, 1 = producer
    const int lane = threadIdx.x & 63;
    const int l = lane & 15;
    const int r = lane >> 4;
    const int b = wid >> 4;
    const int i = ((wid & 15) << 2) + r;

    if (wv == 1) {
        // ---- producer ----
        #pragma unroll
        for (int j = 0; j < 16; ++j)
            dma16(proj + ((size_t)j * B_DIM + b) * NT + 4 * lane, &bufA[j][0]);
        __syncthreads();                      // prologue: bufA ready
        for (int t0 = 0; t0 < T_DIM; t0 += 32) {
            #pragma unroll
            for (int j = 0; j < 16; ++j) {
                int row = t0 + 16 + j; if (row > T_DIM - 1) row = T_DIM - 1;
                dma16(proj + ((size_t)row * B_DIM + b) * NT + 4 * lane, &bufB[j][0]);
            }
            __syncthreads();                  // bufB ready / bufA consumed
            #pragma unroll
            for (int j = 0; j < 16; ++j) {
                int row = t0 + 32 + j; if (row > T_DIM - 1) row = T_DIM - 1;
                dma16(proj + ((size_t)row * B_DIM + b) * NT + 4 * lane, &bufA[j][0]);
            }
            __syncthreads();                  // bufA ready / bufB consumed
        }
    } else {
        // ---- consumer ----
        float4 s = *(const float4*)(S0 + ((size_t)(b * 64 + i) << 6) + 4 * l);
        __syncthreads();                      // wait prologue
        for (int t0 = 0; t0 < T_DIM; t0 += 32) {
            phase16(bufA, t0, s, l, i, b, out);
            __syncthreads();
            phase16(bufB, t0 + 16, s, l, i, b, out);
            __syncthreads();
        }
        *(float4*)(out + (size_t)T_DIM * B_DIM * N_DIM +
                   ((size_t)(b * 64 + i) << 6) + 4 * l) = s;
    }
}

extern "C" void kernel_launch(void* const* d_in, const int* in_sizes, int n_in,
                              void* d_out, int out_size, void* d_ws, size_t ws_size,
                              hipStream_t stream) {
    const float* x  = (const float*)d_in[0];
    const float* S0 = (const float*)d_in[1];
    const float* Wk = (const float*)d_in[2];
    const float* Wv = (const float*)d_in[3];
    const float* Wq = (const float*)d_in[4];
    const float* Wb = (const float*)d_in[5];
    const float* bb = (const float*)d_in[6];
    float* out  = (float*)d_out;
    float* proj = (float*)d_ws;   // 32768 * 256 floats = 32 MB

    proj_gemm<<<dim3(32768 / MT), dim3(256), 0, stream>>>(x, Wk, Wv, Wq, Wb, bb, proj);
    knorm_kernel<<<dim3((32768 * 64) / 256), dim3(256), 0, stream>>>(proj);
    recur5_kernel<<<dim3(256), dim3(128), 0, stream>>>(proj, S0, out);
}

// Round 7
// 763.409 us; speedup vs baseline: 1.7349x; 1.2188x over previous
//
#include <hip/hip_runtime.h>
#include <math.h>

#define T_DIM 2048
#define B_DIM 16
#define D_DIM 1024
#define N_DIM 64
#define EPSV 1e-6f

// proj layout: proj[m][c], m = t*B + b in [0, 32768), c: 0-63 k(->k_norm), 64-127 v, 128-191 q, 192-255 beta(sigmoided)
#define KC 32
#define MT 64
#define NT 256

#define TWO_LOG2E 2.885390081777927f   // 2*log2(e)
#define LOG2E     1.4426950408889634f

// ---- hand-rolled fast math: harness compiles WITHOUT -ffast-math, so plain
// '/' emits the ~10-instr IEEE div sequence. v_rcp_f32 is 1 instr, ~1e-7 rel
// err; absmax threshold here is ~9.0 so this is free accuracy-wise. ----
__device__ __forceinline__ float fast_rcp(float x) {
    return __builtin_amdgcn_rcpf(x);
}
__device__ __forceinline__ float sigmoid_fast(float x) {
    // 1/(1+2^(-log2e*x))
    return fast_rcp(1.f + __builtin_amdgcn_exp2f(-LOG2E * x));
}
// tanh(x) = 1 - 2/(2^(2*log2e*x)+1); caller pre-scales by TWO_LOG2E
__device__ __forceinline__ float tanh_from_scaled(float xs) {
    float e = __builtin_amdgcn_exp2f(xs);
    return 1.f - 2.f * fast_rcp(e + 1.f);
}

// DPP all-reduce within each 16-lane row: quad_perm xor1, xor2, row_ror:4, row_ror:8.
template<int CTRL>
__device__ __forceinline__ float dpp_radd(float x) {
    int y = __builtin_amdgcn_update_dpp(0, __float_as_int(x), CTRL, 0xf, 0xf, true);
    return x + __int_as_float(y);
}
__device__ __forceinline__ float reduce16(float x) {
    x = dpp_radd<0xB1>(x);    // quad_perm [1,0,3,2]
    x = dpp_radd<0x4E>(x);    // quad_perm [2,3,0,1]
    x = dpp_radd<0x124>(x);   // row_ror:4
    x = dpp_radd<0x128>(x);   // row_ror:8
    return x;
}

// async global -> LDS DMA, 16 B per lane; LDS base wave-uniform, lane i -> base + 16*i
__device__ __forceinline__ void dma16(const float* g, float* l) {
    __builtin_amdgcn_global_load_lds((const __attribute__((address_space(1))) void*)g,
                                     (__attribute__((address_space(3))) void*)l, 16, 0, 0);
}

__global__ __launch_bounds__(256) void proj_gemm(
    const float* __restrict__ x,
    const float* __restrict__ Wk, const float* __restrict__ Wv,
    const float* __restrict__ Wq, const float* __restrict__ Wb,
    const float* __restrict__ bb,
    float* __restrict__ proj)
{
    __shared__ float xs[KC][MT + 4];
    __shared__ float wsm[KC][NT + 4];
    const int tid = threadIdx.x;
    const int m0 = blockIdx.x * MT;
    const int tr = tid & 7;
    const int tc = tid >> 3;
    const float* Wmat[4] = {Wk, Wv, Wq, Wb};

    float acc[8][8];
    #pragma unroll
    for (int r = 0; r < 8; ++r)
        #pragma unroll
        for (int c = 0; c < 8; ++c) acc[r][c] = 0.f;

    for (int ch = 0; ch < D_DIM / KC; ++ch) {
        const int kb = ch * KC;
        #pragma unroll
        for (int p = 0; p < 2; ++p) {
            int idx = tid + p * 256;
            int row = idx >> 3, kq = idx & 7;
            const float4 a = *(const float4*)(x + (size_t)(m0 + row) * D_DIM + kb + 4 * kq);
            xs[4*kq+0][row] = a.x; xs[4*kq+1][row] = a.y;
            xs[4*kq+2][row] = a.z; xs[4*kq+3][row] = a.w;
        }
        #pragma unroll
        for (int p = 0; p < 8; ++p) {
            int idx = tid + p * 256;
            int c = idx >> 3, kq = idx & 7;
            const float* Wsrc = Wmat[c >> 6];
            const float4 a = *(const float4*)(Wsrc + (size_t)(c & 63) * D_DIM + kb + 4 * kq);
            wsm[4*kq+0][c] = a.x; wsm[4*kq+1][c] = a.y;
            wsm[4*kq+2][c] = a.z; wsm[4*kq+3][c] = a.w;
        }
        __syncthreads();
        #pragma unroll
        for (int kk = 0; kk < KC; ++kk) {
            float4 a0 = *(const float4*)&xs[kk][8 * tr];
            float4 a1 = *(const float4*)&xs[kk][8 * tr + 4];
            float4 b0 = *(const float4*)&wsm[kk][4 * tc];
            float4 b1 = *(const float4*)&wsm[kk][128 + 4 * tc];
            float av[8] = {a0.x, a0.y, a0.z, a0.w, a1.x, a1.y, a1.z, a1.w};
            float bv[8] = {b0.x, b0.y, b0.z, b0.w, b1.x, b1.y, b1.z, b1.w};
            #pragma unroll
            for (int r = 0; r < 8; ++r)
                #pragma unroll
                for (int c = 0; c < 8; ++c)
                    acc[r][c] += av[r] * bv[c];
        }
        __syncthreads();
    }

    const bool isbeta = (tc >= 16);
    float bias[4] = {0.f, 0.f, 0.f, 0.f};
    if (isbeta) {
        #pragma unroll
        for (int cc = 0; cc < 4; ++cc) bias[cc] = bb[4 * tc - 64 + cc];
    }
    #pragma unroll
    for (int r = 0; r < 8; ++r) {
        const size_t row = (size_t)(m0 + 8 * tr + r);
        float4 ga = make_float4(acc[r][0], acc[r][1], acc[r][2], acc[r][3]);
        float4 gb = make_float4(acc[r][4], acc[r][5], acc[r][6], acc[r][7]);
        if (isbeta) {
            gb.x = sigmoid_fast(gb.x + bias[0]);
            gb.y = sigmoid_fast(gb.y + bias[1]);
            gb.z = sigmoid_fast(gb.z + bias[2]);
            gb.w = sigmoid_fast(gb.w + bias[3]);
        }
        *(float4*)(proj + row * NT + 4 * tc)       = ga;
        *(float4*)(proj + row * NT + 128 + 4 * tc) = gb;
    }
}

__global__ __launch_bounds__(256) void knorm_kernel(float* __restrict__ proj)
{
    const int w = (int)((blockIdx.x * blockDim.x + threadIdx.x) >> 6);
    const int lane = threadIdx.x & 63;
    float k = proj[(size_t)w * NT + lane];
    float s = k * k;
    #pragma unroll
    for (int off = 32; off; off >>= 1) s += __shfl_xor(s, off, 64);
    proj[(size_t)w * NT + lane] = k * fast_rcp(sqrtf(s) + EPSV);
}

// One 16-step compute phase out of an already-filled LDS buffer.
__device__ __forceinline__ void phase16(const float (*buf)[256], int t0,
                                        float4& s, int l, int i, int b,
                                        float* __restrict__ out)
{
    float4 kr[2], qr[2];
    float  vr[2], ber[2];
    #pragma unroll
    for (int j = 0; j < 2; ++j) {
        const float* src = &buf[j][0];
        kr[j]  = *(const float4*)(src + 4 * l);
        qr[j]  = *(const float4*)(src + 128 + 4 * l);
        vr[j]  = src[64 + i];
        ber[j] = src[192 + i];
    }
    #pragma unroll
    for (int sp = 0; sp < 16; ++sp) {
        const float4 kn = kr[sp & 1];
        const float4 q  = qr[sp & 1];
        const float  v  = vr[sp & 1];
        const float  be = ber[sp & 1];
        if (sp + 2 < 16) {   // static (unrolled): ring never crosses the barrier
            const float* src = &buf[sp + 2][0];
            kr[sp & 1]  = *(const float4*)(src + 4 * l);
            qr[sp & 1]  = *(const float4*)(src + 128 + 4 * l);
            vr[sp & 1]  = src[64 + i];
            ber[sp & 1] = src[192 + i];
        }
        float y2 = (s.x * kn.x + s.y * kn.y) + (s.z * kn.z + s.w * kn.w);
        y2 = reduce16(y2);
        const float delta = (v - y2) * TWO_LOG2E;
        const float bes = be * TWO_LOG2E;
        s.x = tanh_from_scaled(fmaf(bes, s.x, delta * kn.x));
        s.y = tanh_from_scaled(fmaf(bes, s.y, delta * kn.y));
        s.z = tanh_from_scaled(fmaf(bes, s.z, delta * kn.z));
        s.w = tanh_from_scaled(fmaf(bes, s.w, delta * kn.w));
        float y1 = (s.x * q.x + s.y * q.y) + (s.z * q.z + s.w * q.w);
        y1 = reduce16(y1);
        if (l == 0) {
            out[(size_t)(t0 + sp) * (B_DIM * N_DIM) + b * 64 + i] =
                y1 * y1 * sigmoid_fast(y1);
        }
    }
}

// Warp-specialized producer/consumer (round-5 structure, kept): producer wave
// issues global_load_lds DMAs; consumer wave only touches LDS + output stores.
__global__ __launch_bounds__(128, 1) void recur5_kernel(
    const float* __restrict__ proj,
    const float* __restrict__ S0,
    float* __restrict__ out)   // [T,B,N] then S_final [B,N,N]
{
    __shared__ float bufA[16][256];
    __shared__ float bufB[16][256];

    const int wid  = blockIdx.x;          // [0,256)
    const int wv   = threadIdx.x >> 6;    // 0 = consumer, 1 = producer
    const int lane = threadIdx.x & 63;
    const int l = lane & 15;
    const int r = lane >> 4;
    const int b = wid >> 4;
    const int i = ((wid & 15) << 2) + r;

    if (wv == 1) {
        // ---- producer ----
        #pragma unroll
        for (int j = 0; j < 16; ++j)
            dma16(proj + ((size_t)j * B_DIM + b) * NT + 4 * lane, &bufA[j][0]);
        __syncthreads();                      // prologue: bufA ready
        for (int t0 = 0; t0 < T_DIM; t0 += 32) {
            #pragma unroll
            for (int j = 0; j < 16; ++j) {
                int row = t0 + 16 + j; if (row > T_DIM - 1) row = T_DIM - 1;
                dma16(proj + ((size_t)row * B_DIM + b) * NT + 4 * lane, &bufB[j][0]);
            }
            __syncthreads();                  // bufB ready / bufA consumed
            #pragma unroll
            for (int j = 0; j < 16; ++j) {
                int row = t0 + 32 + j; if (row > T_DIM - 1) row = T_DIM - 1;
                dma16(proj + ((size_t)row * B_DIM + b) * NT + 4 * lane, &bufA[j][0]);
            }
            __syncthreads();                  // bufA ready / bufB consumed
        }
    } else {
        // ---- consumer ----
        float4 s = *(const float4*)(S0 + ((size_t)(b * 64 + i) << 6) + 4 * l);
        __syncthreads();                      // wait prologue
        for (int t0 = 0; t0 < T_DIM; t0 += 32) {
            phase16(bufA, t0, s, l, i, b, out);
            __syncthreads();
            phase16(bufB, t0 + 16, s, l, i, b, out);
            __syncthreads();
        }
        *(float4*)(out + (size_t)T_DIM * B_DIM * N_DIM +
                   ((size_t)(b * 64 + i) << 6) + 4 * l) = s;
    }
}

extern "C" void kernel_launch(void* const* d_in, const int* in_sizes, int n_in,
                              void* d_out, int out_size, void* d_ws, size_t ws_size,
                              hipStream_t stream) {
    const float* x  = (const float*)d_in[0];
    const float* S0 = (const float*)d_in[1];
    const float* Wk = (const float*)d_in[2];
    const float* Wv = (const float*)d_in[3];
    const float* Wq = (const float*)d_in[4];
    const float* Wb = (const float*)d_in[5];
    const float* bb = (const float*)d_in[6];
    float* out  = (float*)d_out;
    float* proj = (float*)d_ws;   // 32768 * 256 floats = 32 MB

    proj_gemm<<<dim3(32768 / MT), dim3(256), 0, stream>>>(x, Wk, Wv, Wq, Wb, bb, proj);
    knorm_kernel<<<dim3((32768 * 64) / 256), dim3(256), 0, stream>>>(proj);
    recur5_kernel<<<dim3(256), dim3(128), 0, stream>>>(proj, S0, out);
}

// Round 8
// 643.525 us; speedup vs baseline: 2.0581x; 1.1863x over previous
//
#include <hip/hip_runtime.h>
#include <math.h>

#define T_DIM 2048
#define B_DIM 16
#define D_DIM 1024
#define N_DIM 64
#define EPSV 1e-6f

// proj layout: proj[m][c], m = t*B + b in [0, 32768), c: 0-63 k(->k_norm), 64-127 v, 128-191 q, 192-255 beta(sigmoided)
#define KC 32
#define MT 64
#define NT 256

#define TWO_LOG2E 2.885390081777927f   // 2*log2(e)
#define LOG2E     1.4426950408889634f

// ---- hand-rolled fast math (harness has no -ffast-math; '/' = ~10-instr IEEE seq) ----
__device__ __forceinline__ float fast_rcp(float x) {
    return __builtin_amdgcn_rcpf(x);
}
__device__ __forceinline__ float sigmoid_fast(float x) {
    return fast_rcp(1.f + __builtin_amdgcn_exp2f(-LOG2E * x));
}
// tanh(x) = 1 - 2/(2^(2*log2e*x)+1); caller pre-scales arg by TWO_LOG2E
__device__ __forceinline__ float tanh_from_scaled(float xs) {
    float e = __builtin_amdgcn_exp2f(xs);
    return 1.f - 2.f * fast_rcp(e + 1.f);
}

// DPP all-reduce within each 16-lane row: quad_perm xor1, xor2, row_ror:4, row_ror:8.
template<int CTRL>
__device__ __forceinline__ float dpp_radd(float x) {
    int y = __builtin_amdgcn_update_dpp(0, __float_as_int(x), CTRL, 0xf, 0xf, true);
    return x + __int_as_float(y);
}
__device__ __forceinline__ float reduce16(float x) {
    x = dpp_radd<0xB1>(x);    // quad_perm [1,0,3,2]
    x = dpp_radd<0x4E>(x);    // quad_perm [2,3,0,1]
    x = dpp_radd<0x124>(x);   // row_ror:4
    x = dpp_radd<0x128>(x);   // row_ror:8
    return x;
}

// async global -> LDS DMA, 16 B per lane; LDS base wave-uniform, lane i -> base + 16*i
__device__ __forceinline__ void dma16(const float* g, float* l) {
    __builtin_amdgcn_global_load_lds((const __attribute__((address_space(1))) void*)g,
                                     (__attribute__((address_space(3))) void*)l, 16, 0, 0);
}

__global__ __launch_bounds__(256) void proj_gemm(
    const float* __restrict__ x,
    const float* __restrict__ Wk, const float* __restrict__ Wv,
    const float* __restrict__ Wq, const float* __restrict__ Wb,
    const float* __restrict__ bb,
    float* __restrict__ proj)
{
    __shared__ float xs[KC][MT + 4];
    __shared__ float wsm[KC][NT + 4];
    const int tid = threadIdx.x;
    const int m0 = blockIdx.x * MT;
    const int tr = tid & 7;
    const int tc = tid >> 3;
    const float* Wmat[4] = {Wk, Wv, Wq, Wb};

    float acc[8][8];
    #pragma unroll
    for (int r = 0; r < 8; ++r)
        #pragma unroll
        for (int c = 0; c < 8; ++c) acc[r][c] = 0.f;

    for (int ch = 0; ch < D_DIM / KC; ++ch) {
        const int kb = ch * KC;
        #pragma unroll
        for (int p = 0; p < 2; ++p) {
            int idx = tid + p * 256;
            int row = idx >> 3, kq = idx & 7;
            const float4 a = *(const float4*)(x + (size_t)(m0 + row) * D_DIM + kb + 4 * kq);
            xs[4*kq+0][row] = a.x; xs[4*kq+1][row] = a.y;
            xs[4*kq+2][row] = a.z; xs[4*kq+3][row] = a.w;
        }
        #pragma unroll
        for (int p = 0; p < 8; ++p) {
            int idx = tid + p * 256;
            int c = idx >> 3, kq = idx & 7;
            const float* Wsrc = Wmat[c >> 6];
            const float4 a = *(const float4*)(Wsrc + (size_t)(c & 63) * D_DIM + kb + 4 * kq);
            wsm[4*kq+0][c] = a.x; wsm[4*kq+1][c] = a.y;
            wsm[4*kq+2][c] = a.z; wsm[4*kq+3][c] = a.w;
        }
        __syncthreads();
        #pragma unroll
        for (int kk = 0; kk < KC; ++kk) {
            float4 a0 = *(const float4*)&xs[kk][8 * tr];
            float4 a1 = *(const float4*)&xs[kk][8 * tr + 4];
            float4 b0 = *(const float4*)&wsm[kk][4 * tc];
            float4 b1 = *(const float4*)&wsm[kk][128 + 4 * tc];
            float av[8] = {a0.x, a0.y, a0.z, a0.w, a1.x, a1.y, a1.z, a1.w};
            float bv[8] = {b0.x, b0.y, b0.z, b0.w, b1.x, b1.y, b1.z, b1.w};
            #pragma unroll
            for (int r = 0; r < 8; ++r)
                #pragma unroll
                for (int c = 0; c < 8; ++c)
                    acc[r][c] += av[r] * bv[c];
        }
        __syncthreads();
    }

    const bool isbeta = (tc >= 16);
    float bias[4] = {0.f, 0.f, 0.f, 0.f};
    if (isbeta) {
        #pragma unroll
        for (int cc = 0; cc < 4; ++cc) bias[cc] = bb[4 * tc - 64 + cc];
    }
    #pragma unroll
    for (int r = 0; r < 8; ++r) {
        const size_t row = (size_t)(m0 + 8 * tr + r);
        float4 ga = make_float4(acc[r][0], acc[r][1], acc[r][2], acc[r][3]);
        float4 gb = make_float4(acc[r][4], acc[r][5], acc[r][6], acc[r][7]);
        if (isbeta) {
            gb.x = sigmoid_fast(gb.x + bias[0]);
            gb.y = sigmoid_fast(gb.y + bias[1]);
            gb.z = sigmoid_fast(gb.z + bias[2]);
            gb.w = sigmoid_fast(gb.w + bias[3]);
        }
        *(float4*)(proj + row * NT + 4 * tc)       = ga;
        *(float4*)(proj + row * NT + 128 + 4 * tc) = gb;
    }
}

__global__ __launch_bounds__(256) void knorm_kernel(float* __restrict__ proj)
{
    const int w = (int)((blockIdx.x * blockDim.x + threadIdx.x) >> 6);
    const int lane = threadIdx.x & 63;
    float k = proj[(size_t)w * NT + lane];
    float s = k * k;
    #pragma unroll
    for (int off = 32; off; off >>= 1) s += __shfl_xor(s, off, 64);
    proj[(size_t)w * NT + lane] = k * fast_rcp(sqrtf(s) + EPSV);
}

// One step of the recurrence. Chain after reduce: y2 -> fma(dC) -> fma(arg)
// -> exp2 -> add -> rcp -> fma. beC*s hoisted off-chain (independent of y2).
// y1 select via cndmask (no exec divergence, no per-step store).
__device__ __forceinline__ void step_body(float4& s, const float4 kn, const float4 q,
                                          const float vC, const float beC,
                                          int sp, int l, float& ysel)
{
    float y2 = (s.x * kn.x + s.y * kn.y) + (s.z * kn.z + s.w * kn.w);
    y2 = reduce16(y2);
    const float dC = fmaf(-TWO_LOG2E, y2, vC);     // (v - y2)*2log2e
    const float bsx = beC * s.x, bsy = beC * s.y;  // overlap with reduce16 stalls
    const float bsz = beC * s.z, bsw = beC * s.w;
    s.x = tanh_from_scaled(fmaf(dC, kn.x, bsx));
    s.y = tanh_from_scaled(fmaf(dC, kn.y, bsy));
    s.z = tanh_from_scaled(fmaf(dC, kn.z, bsz));
    s.w = tanh_from_scaled(fmaf(dC, kn.w, bsw));
    float y1 = (s.x * q.x + s.y * q.y) + (s.z * q.z + s.w * q.w);
    y1 = reduce16(y1);
    ysel = (l == sp) ? y1 : ysel;                  // lane l keeps step sp==l
}

// Compact 16-step phase: 2-step unrolled loop (8 iters, ~1 KB body -> fits
// I-cache; round-7's fully-unrolled ~18 KB body is the suspected serial
// I-fetch-miss stall). Depth-2 register ring, prefetch distance 1 iter.
__device__ __forceinline__ void phase16(const float (*buf)[256], int t0,
                                        float4& s, int l, int i, int b,
                                        float* __restrict__ out)
{
    const float* s0 = &buf[0][0];
    const float* s1 = &buf[1][0];
    float4 kn0 = *(const float4*)(s0 + 4 * l);
    float4 q0  = *(const float4*)(s0 + 128 + 4 * l);
    float  vC0 = s0[64 + i] * TWO_LOG2E;
    float  beC0= s0[192 + i] * TWO_LOG2E;
    float4 kn1 = *(const float4*)(s1 + 4 * l);
    float4 q1  = *(const float4*)(s1 + 128 + 4 * l);
    float  vC1 = s1[64 + i] * TWO_LOG2E;
    float  beC1= s1[192 + i] * TWO_LOG2E;

    float ysel = 0.f;
    for (int j = 0; j < 8; ++j) {
        const int sp = 2 * j;
        // prefetch next iteration's rows (clamped; row-15 re-read is harmless)
        const int p2 = (sp + 2 < 16) ? sp + 2 : 15;
        const int p3 = (sp + 3 < 16) ? sp + 3 : 15;
        const float* sA = &buf[p2][0];
        const float* sB = &buf[p3][0];
        float4 knA = *(const float4*)(sA + 4 * l);
        float4 qA  = *(const float4*)(sA + 128 + 4 * l);
        float  vCA = sA[64 + i] * TWO_LOG2E;
        float  beCA= sA[192 + i] * TWO_LOG2E;
        float4 knB = *(const float4*)(sB + 4 * l);
        float4 qB  = *(const float4*)(sB + 128 + 4 * l);
        float  vCB = sB[64 + i] * TWO_LOG2E;
        float  beCB= sB[192 + i] * TWO_LOG2E;

        step_body(s, kn0, q0, vC0, beC0, sp,     l, ysel);
        step_body(s, kn1, q1, vC1, beC1, sp + 1, l, ysel);

        kn0 = knA; q0 = qA; vC0 = vCA; beC0 = beCA;
        kn1 = knB; q1 = qB; vC1 = vCB; beC1 = beCB;
    }
    // one coalesced store per lane: lane l holds y1 of step t0+l for its row i
    const float w = ysel;
    out[(size_t)(t0 + l) * (B_DIM * N_DIM) + b * 64 + i] = w * w * sigmoid_fast(w);
}

// Warp-specialized producer/consumer (kept from round 5): producer wave issues
// global_load_lds DMAs; consumer wave touches only LDS + phase-end stores.
__global__ __launch_bounds__(128, 1) void recur6_kernel(
    const float* __restrict__ proj,
    const float* __restrict__ S0,
    float* __restrict__ out)   // [T,B,N] then S_final [B,N,N]
{
    __shared__ float bufA[16][256];
    __shared__ float bufB[16][256];

    const int wid  = blockIdx.x;          // [0,256)
    const int wv   = threadIdx.x >> 6;    // 0 = consumer, 1 = producer
    const int lane = threadIdx.x & 63;
    const int l = lane & 15;
    const int r = lane >> 4;
    const int b = wid >> 4;
    const int i = ((wid & 15) << 2) + r;

    if (wv == 1) {
        // ---- producer ----
        #pragma unroll
        for (int j = 0; j < 16; ++j)
            dma16(proj + ((size_t)j * B_DIM + b) * NT + 4 * lane, &bufA[j][0]);
        __syncthreads();                      // prologue: bufA ready
        for (int t0 = 0; t0 < T_DIM; t0 += 32) {
            #pragma unroll
            for (int j = 0; j < 16; ++j) {
                int row = t0 + 16 + j; if (row > T_DIM - 1) row = T_DIM - 1;
                dma16(proj + ((size_t)row * B_DIM + b) * NT + 4 * lane, &bufB[j][0]);
            }
            __syncthreads();                  // bufB ready / bufA consumed
            #pragma unroll
            for (int j = 0; j < 16; ++j) {
                int row = t0 + 32 + j; if (row > T_DIM - 1) row = T_DIM - 1;
                dma16(proj + ((size_t)row * B_DIM + b) * NT + 4 * lane, &bufA[j][0]);
            }
            __syncthreads();                  // bufA ready / bufB consumed
        }
    } else {
        // ---- consumer ----
        float4 s = *(const float4*)(S0 + ((size_t)(b * 64 + i) << 6) + 4 * l);
        __syncthreads();                      // wait prologue
        for (int t0 = 0; t0 < T_DIM; t0 += 32) {
            phase16(bufA, t0, s, l, i, b, out);
            __syncthreads();
            phase16(bufB, t0 + 16, s, l, i, b, out);
            __syncthreads();
        }
        *(float4*)(out + (size_t)T_DIM * B_DIM * N_DIM +
                   ((size_t)(b * 64 + i) << 6) + 4 * l) = s;
    }
}

extern "C" void kernel_launch(void* const* d_in, const int* in_sizes, int n_in,
                              void* d_out, int out_size, void* d_ws, size_t ws_size,
                              hipStream_t stream) {
    const float* x  = (const float*)d_in[0];
    const float* S0 = (const float*)d_in[1];
    const float* Wk = (const float*)d_in[2];
    const float* Wv = (const float*)d_in[3];
    const float* Wq = (const float*)d_in[4];
    const float* Wb = (const float*)d_in[5];
    const float* bb = (const float*)d_in[6];
    float* out  = (float*)d_out;
    float* proj = (float*)d_ws;   // 32768 * 256 floats = 32 MB

    proj_gemm<<<dim3(32768 / MT), dim3(256), 0, stream>>>(x, Wk, Wv, Wq, Wb, bb, proj);
    knorm_kernel<<<dim3((32768 * 64) / 256), dim3(256), 0, stream>>>(proj);
    recur6_kernel<<<dim3(256), dim3(128), 0, stream>>>(proj, S0, out);
}